// Round 7
// baseline (189.405 us; speedup 1.0000x reference)
//
#include <hip/hip_runtime.h>

#define NGRAPHS 256
#define NMAX 2048        // max nodes/graph in pool LDS (actual ~490)

// ---- k1: node dots (32 rows/block, 16 lanes/row, float4/lane) + graph
//      boundaries + inline zero of agg[] (replaces memset kernel). ----
__global__ __launch_bounds__(512) void k1_dot(
    const float* __restrict__ x,
    const int*   __restrict__ batch,
    const float* __restrict__ w_rel,
    const float* __restrict__ w_root,
    float* __restrict__ p, float* __restrict__ r,
    float* __restrict__ agg,
    int* __restrict__ starts, int* __restrict__ ends, int N)
{
    int tid = threadIdx.x;
    int row = (int)blockIdx.x * 32 + (tid >> 4);
    int fq  = tid & 15;
    if (row >= N) return;
    if (fq == 0) {                       // graph boundaries (handles empty graphs)
        agg[row] = 0.0f;                 // zero aggregation buffer inline
        int b = batch[row];
        if (row == 0) {
            for (int g = 0; g < b; ++g) { starts[g] = 0; ends[g] = 0; }
            starts[b] = 0;
        } else {
            int bp = batch[row - 1];
            if (bp != b) {
                ends[bp] = row;
                for (int g = bp + 1; g < b; ++g) { starts[g] = row; ends[g] = row; }
                starts[b] = row;
            }
        }
        if (row == N - 1) {
            ends[b] = N;
            for (int g = b + 1; g < NGRAPHS; ++g) { starts[g] = N; ends[g] = N; }
        }
    }
    float4 v  = *(const float4*)(x + (size_t)row * 64 + fq * 4);
    float4 wr = ((const float4*)w_rel)[fq];
    float4 wo = ((const float4*)w_root)[fq];
    float a = v.x * wr.x + v.y * wr.y + v.z * wr.z + v.w * wr.w;
    float c = v.x * wo.x + v.y * wo.y + v.z * wo.z + v.w * wo.w;
    a += __shfl_down(a, 8); c += __shfl_down(c, 8);
    a += __shfl_down(a, 4); c += __shfl_down(c, 4);
    a += __shfl_down(a, 2); c += __shfl_down(c, 2);
    a += __shfl_down(a, 1); c += __shfl_down(c, 1);
    if (fq == 0) { p[row] = a; r[row] = c; }
}

// ---- k2: single pass over edges. int4 loads, p[src] gather (L2-resident),
//      native global f32 atomic add into agg[dst] (~16 adds/address avg,
//      L2-resident 400KB -> low contention). ----
__global__ __launch_bounds__(256) void k2_scatter4(
    const int* __restrict__ ei,          // [2,E]: src then dst
    const float* __restrict__ p,
    float* __restrict__ agg, int E)
{
    int i = (int)blockIdx.x * 256 + threadIdx.x;   // quad index (E%4==0)
    int q = E >> 2;
    if (i >= q) return;
    const int4* s4 = (const int4*)ei;
    const int4* d4 = (const int4*)(ei + E);
    int4 s = s4[i];
    int4 d = d4[i];
    float v0 = p[s.x], v1 = p[s.y], v2 = p[s.z], v3 = p[s.w];
    unsafeAtomicAdd(&agg[d.x], v0);
    unsafeAtomicAdd(&agg[d.y], v1);
    unsafeAtomicAdd(&agg[d.z], v2);
    unsafeAtomicAdd(&agg[d.w], v3);
}

__global__ __launch_bounds__(256) void k2_scatter1(
    const int* __restrict__ ei,
    const float* __restrict__ p,
    float* __restrict__ agg, int E)
{
    int i = (int)blockIdx.x * 256 + threadIdx.x;
    if (i < E) unsafeAtomicAdd(&agg[ei[E + i]], p[ei[i]]);
}

// ---- k4: per-graph. Computes score = tanh(agg + b + r) inline while
//      loading (kills the separate score kernel + round-trip), then stable
//      top-k rank (float4 LDS j-loop) + compacted float4 weighted pool. ----
__global__ __launch_bounds__(512) void k4_pool(
    const float* __restrict__ x,
    const float* __restrict__ agg,
    const float* __restrict__ r,
    const float* __restrict__ brel,
    const int* __restrict__ starts,
    const int* __restrict__ ends,
    float* __restrict__ out)
{
    __shared__ __align__(16) float sc[NMAX];
    __shared__ int   kidx[NMAX / 2 + 64];
    __shared__ float kw[NMAX / 2 + 64];
    __shared__ float accs[8][64][4];
    __shared__ int   pctr;

    int g   = blockIdx.x;
    int tid = threadIdx.x;
    int start = starts[g];
    int n     = ends[g] - start;
    if (n > NMAX) n = NMAX;              // safety clamp (never hit)
    int k = (n + 1) >> 1;                // ceil(0.5*n) == kept count
    if (tid == 0) pctr = 0;

    float bb = brel[0];
    for (int i = tid; i < n; i += 512)
        sc[i] = tanhf(agg[start + i] + bb + r[start + i]);
    __syncthreads();

    // stable rank (lexsort tie-break: score desc, index asc) + compaction
    int n4 = n & ~3;
    for (int i = tid; i < n; i += 512) {
        float si = sc[i];
        int rank = 0;
        int j = 0;
        for (; j < n4; j += 4) {
            float4 s4 = *(const float4*)&sc[j];
            rank += (s4.x > si) || (s4.x == si && (j + 0) < i);
            rank += (s4.y > si) || (s4.y == si && (j + 1) < i);
            rank += (s4.z > si) || (s4.z == si && (j + 2) < i);
            rank += (s4.w > si) || (s4.w == si && (j + 3) < i);
        }
        for (; j < n; ++j) {
            float sj = sc[j];
            rank += (sj > si) || (sj == si && j < i);
        }
        if (rank < k) {
            int pos = atomicAdd(&pctr, 1);
            kidx[pos] = i;
            kw[pos]   = si;
        }
    }
    __syncthreads();
    int k32 = (k + 31) & ~31;
    for (int e = k + tid; e < k32; e += 512) { kidx[e] = 0; kw[e] = 0.0f; }
    __syncthreads();

    // weighted pool over compacted kept list: each 16-lane group reads one
    // contiguous 256B row
    int wg   = tid >> 6;
    int lane = tid & 63;
    int rgrp = lane >> 4;
    int fq   = lane & 15;
    float a0 = 0.0f, a1 = 0.0f, a2 = 0.0f, a3 = 0.0f;
    #pragma unroll 2
    for (int e = wg * 4 + rgrp; e < k32; e += 32) {
        float wv = kw[e];
        int row  = start + kidx[e];
        const float4 v = *(const float4*)(x + (size_t)row * 64 + fq * 4);
        a0 += v.x * wv; a1 += v.y * wv; a2 += v.z * wv; a3 += v.w * wv;
    }
    accs[wg][lane][0] = a0; accs[wg][lane][1] = a1;
    accs[wg][lane][2] = a2; accs[wg][lane][3] = a3;
    __syncthreads();
    if (tid < 64) {
        float sum = 0.0f;
        #pragma unroll
        for (int gg = 0; gg < 8; ++gg)
            #pragma unroll
            for (int rg = 0; rg < 4; ++rg)
                sum += accs[gg][rg * 16 + (tid >> 2)][tid & 3];
        out[(size_t)g * 64 + tid] = sum / fmaxf((float)k, 1.0f);
    }
}

extern "C" void kernel_launch(void* const* d_in, const int* in_sizes, int n_in,
                              void* d_out, int out_size, void* d_ws, size_t ws_size,
                              hipStream_t stream) {
    const float* x      = (const float*)d_in[0];
    const int*   ei     = (const int*)  d_in[1];
    const int*   batch  = (const int*)  d_in[2];
    const float* w_rel  = (const float*)d_in[3];
    const float* b_rel  = (const float*)d_in[4];
    const float* w_root = (const float*)d_in[5];
    float* out = (float*)d_out;

    int N = in_sizes[2];
    int E = in_sizes[1] / 2;
    int dotblks = (N + 31) / 32;

    // ws layout (4B units): p[N], r[N], agg[N], starts[256], ends[256]
    float* p      = (float*)d_ws;
    float* r      = p + (size_t)N;
    float* agg    = r + (size_t)N;
    int*   starts = (int*)(agg + (size_t)N);
    int*   ends   = starts + NGRAPHS;

    k1_dot<<<dotblks, 512, 0, stream>>>(x, batch, w_rel, w_root,
                                        p, r, agg, starts, ends, N);
    if ((E & 3) == 0) {
        int q = E >> 2;
        k2_scatter4<<<(q + 255) / 256, 256, 0, stream>>>(ei, p, agg, E);
    } else {
        k2_scatter1<<<(E + 255) / 256, 256, 0, stream>>>(ei, p, agg, E);
    }
    k4_pool<<<NGRAPHS, 512, 0, stream>>>(x, agg, r, b_rel, starts, ends, out);
}

// Round 8
// 138.424 us; speedup vs baseline: 1.3683x; 1.3683x over previous
//
#include <hip/hip_runtime.h>

#define NGRAPHS 256
#define BINR   128       // nodes per dst-range bin (bin = dst >> 7)
#define MAXB   1024      // max padded bins (N <= 131072)
#define SBLK   512       // scatter blocks == kB threads (cell row length)
#define CAPC   24        // entries per (block,bin) cell; Poisson(4) tail ~2e-12
#define BINCAP (SBLK * CAPC)   // 12288 entries per bin region
#define NMAX   2048      // max nodes/graph in pool LDS (actual ~490)

// =====================================================================
// kA: fused roles, single edge sweep, NO count pass / scan / reserve.
//  Blocks [0,SBLK): for each edge in chunk: b=dst>>7, pos=LDS-bump(cur[b]),
//    write bucket[b*BINCAP + blk*CAPC + pos] (static per-(block,bin) cell).
//    After sweep: Ct[b*SBLK + blk] = min(cur[b],CAPC).
//  Blocks [SBLK,..): float4 node dots (32 rows/block) + graph boundaries.
// =====================================================================
__global__ __launch_bounds__(512) void kA_fused(
    const float* __restrict__ x,
    const int*   __restrict__ batch,
    const int*   __restrict__ ei,        // [2,E]: src then dst
    const float* __restrict__ w_rel,
    const float* __restrict__ w_root,
    float* __restrict__ p, float* __restrict__ r,
    int* __restrict__ starts, int* __restrict__ ends,
    int* __restrict__ Ct,                // [NBINSP][SBLK] cell counts
    unsigned* __restrict__ bucket,       // [NBINSP][BINCAP]
    int N, int E, int chunkE, int NBINSP, int vecE)
{
    __shared__ int cur[MAXB];
    int tid = threadIdx.x;
    int blk = (int)blockIdx.x;

    if (blk < SBLK) {                    // ---- scatter role ----
        if (E <= 0) return;              // fallback path: role disabled
        for (int b = tid; b < NBINSP; b += 512) cur[b] = 0;
        __syncthreads();
        int beg = blk * chunkE;
        int end = min(beg + chunkE, E);
        unsigned cellbase = (unsigned)blk * CAPC;
        if (vecE) {
            const int4* s4 = (const int4*)ei;
            const int4* d4 = (const int4*)(ei + E);
            for (int i = (beg >> 2) + tid; i < (end >> 2); i += 512) {
                int4 d = d4[i];
                int4 s = s4[i];
                int b0 = d.x >> 7, p0 = atomicAdd(&cur[b0], 1);
                if (p0 < CAPC) bucket[(size_t)b0 * BINCAP + cellbase + p0] =
                    ((unsigned)s.x << 7) | (unsigned)(d.x & 127);
                int b1 = d.y >> 7, p1 = atomicAdd(&cur[b1], 1);
                if (p1 < CAPC) bucket[(size_t)b1 * BINCAP + cellbase + p1] =
                    ((unsigned)s.y << 7) | (unsigned)(d.y & 127);
                int b2 = d.z >> 7, p2 = atomicAdd(&cur[b2], 1);
                if (p2 < CAPC) bucket[(size_t)b2 * BINCAP + cellbase + p2] =
                    ((unsigned)s.z << 7) | (unsigned)(d.z & 127);
                int b3 = d.w >> 7, p3 = atomicAdd(&cur[b3], 1);
                if (p3 < CAPC) bucket[(size_t)b3 * BINCAP + cellbase + p3] =
                    ((unsigned)s.w << 7) | (unsigned)(d.w & 127);
            }
        } else {
            for (int i = beg + tid; i < end; i += 512) {
                int s = ei[i];
                int d = ei[E + i];
                int b = d >> 7;
                int pos = atomicAdd(&cur[b], 1);
                if (pos < CAPC) bucket[(size_t)b * BINCAP + cellbase + pos] =
                    ((unsigned)s << 7) | (unsigned)(d & 127);
            }
        }
        __syncthreads();
        for (int b = tid; b < NBINSP; b += 512)
            Ct[(size_t)b * SBLK + blk] = min(cur[b], CAPC);
        return;
    }

    // ---- node-dot role: 32 rows/block, 16 lanes/row, float4/lane ----
    int row = (blk - SBLK) * 32 + (tid >> 4);
    int fq  = tid & 15;
    if (row >= N) return;
    if (fq == 0) {                       // graph boundaries (handles empty graphs)
        int b = batch[row];
        if (row == 0) {
            for (int g = 0; g < b; ++g) { starts[g] = 0; ends[g] = 0; }
            starts[b] = 0;
        } else {
            int bp = batch[row - 1];
            if (bp != b) {
                ends[bp] = row;
                for (int g = bp + 1; g < b; ++g) { starts[g] = row; ends[g] = row; }
                starts[b] = row;
            }
        }
        if (row == N - 1) {
            ends[b] = N;
            for (int g = b + 1; g < NGRAPHS; ++g) { starts[g] = N; ends[g] = N; }
        }
    }
    float4 v  = *(const float4*)(x + (size_t)row * 64 + fq * 4);
    float4 wr = ((const float4*)w_rel)[fq];
    float4 wo = ((const float4*)w_root)[fq];
    float a = v.x * wr.x + v.y * wr.y + v.z * wr.z + v.w * wr.w;
    float c = v.x * wo.x + v.y * wo.y + v.z * wo.z + v.w * wo.w;
    a += __shfl_down(a, 8); c += __shfl_down(c, 8);
    a += __shfl_down(a, 4); c += __shfl_down(c, 4);
    a += __shfl_down(a, 2); c += __shfl_down(c, 2);
    a += __shfl_down(a, 1); c += __shfl_down(c, 1);
    if (fq == 0) { p[row] = a; r[row] = c; }
}

// ---- kB: one block per bin. Thread t consumes cell (bin, t): coalesced
//      count read, short run read (avg 4 entries), LDS f32 atomics into
//      acc[128], fused tanh -> final per-node score. ----
__global__ __launch_bounds__(512) void kB_score(
    const unsigned* __restrict__ bucket,
    const int* __restrict__ Ct,
    const float* __restrict__ p,
    const float* __restrict__ r,
    const float* __restrict__ brel,
    float* __restrict__ score, int N)
{
    __shared__ float acc[BINR];
    int tid = threadIdx.x;
    int b   = blockIdx.x;
    if (tid < BINR) acc[tid] = 0.0f;
    __syncthreads();
    int c = Ct[(size_t)b * SBLK + tid];            // coalesced 2KB row
    size_t base = (size_t)b * BINCAP + (size_t)tid * CAPC;
    for (int j = 0; j < c; ++j) {
        unsigned u = bucket[base + j];
        atomicAdd(&acc[u & 127u], p[u >> 7]);      // ds_add_f32
    }
    __syncthreads();
    int node = b * BINR + tid;
    if (tid < BINR && node < N)
        score[node] = tanhf(acc[tid] + brel[0] + r[node]);
}

// ---- fallback (guards fail): zero + device-scope atomic scatter + score ----
__global__ __launch_bounds__(256) void kZ_zero(float* __restrict__ a, int N)
{
    int i = blockIdx.x * 256 + threadIdx.x;
    if (i < N) a[i] = 0.0f;
}
__global__ __launch_bounds__(256) void k2_scatter(
    const int* __restrict__ ei, const float* __restrict__ p,
    float* aggdot, int E)
{
    int i = blockIdx.x * 256 + threadIdx.x;
    if (i < E) unsafeAtomicAdd(&aggdot[ei[E + i]], p[ei[i]]);
}
__global__ __launch_bounds__(256) void kS_score(
    const float* __restrict__ aggdot, const float* __restrict__ r,
    const float* __restrict__ brel, float* __restrict__ score, int N)
{
    int i = blockIdx.x * 256 + threadIdx.x;
    if (i < N) score[i] = tanhf(aggdot[i] + brel[0] + r[i]);
}

// ---- k4: per-graph stable top-k rank (float4 LDS j-loop) + compacted
//      float4 weighted pool ----
__global__ __launch_bounds__(512) void k4_pool(
    const float* __restrict__ x,
    const float* __restrict__ score,
    const int* __restrict__ starts,
    const int* __restrict__ ends,
    float* __restrict__ out)
{
    __shared__ __align__(16) float sc[NMAX];
    __shared__ int   kidx[NMAX / 2 + 64];
    __shared__ float kw[NMAX / 2 + 64];
    __shared__ float accs[8][64][4];
    __shared__ int   pctr;

    int g   = blockIdx.x;
    int tid = threadIdx.x;
    int start = starts[g];
    int n     = ends[g] - start;
    if (n > NMAX) n = NMAX;              // safety clamp (never hit)
    int k = (n + 1) >> 1;                // ceil(0.5*n) == kept count
    if (tid == 0) pctr = 0;

    for (int i = tid; i < n; i += 512) sc[i] = score[start + i];
    __syncthreads();

    // stable rank (lexsort tie-break: score desc, index asc) + compaction
    int n4 = n & ~3;
    for (int i = tid; i < n; i += 512) {
        float si = sc[i];
        int rank = 0;
        int j = 0;
        for (; j < n4; j += 4) {
            float4 s4 = *(const float4*)&sc[j];
            rank += (s4.x > si) || (s4.x == si && (j + 0) < i);
            rank += (s4.y > si) || (s4.y == si && (j + 1) < i);
            rank += (s4.z > si) || (s4.z == si && (j + 2) < i);
            rank += (s4.w > si) || (s4.w == si && (j + 3) < i);
        }
        for (; j < n; ++j) {
            float sj = sc[j];
            rank += (sj > si) || (sj == si && j < i);
        }
        if (rank < k) {
            int pos = atomicAdd(&pctr, 1);
            kidx[pos] = i;
            kw[pos]   = si;
        }
    }
    __syncthreads();
    int k32 = (k + 31) & ~31;
    for (int e = k + tid; e < k32; e += 512) { kidx[e] = 0; kw[e] = 0.0f; }
    __syncthreads();

    // weighted pool over compacted kept list: each 16-lane group reads one
    // contiguous 256B row (L3-resident from kA's x pass)
    int wg   = tid >> 6;
    int lane = tid & 63;
    int rgrp = lane >> 4;
    int fq   = lane & 15;
    float a0 = 0.0f, a1 = 0.0f, a2 = 0.0f, a3 = 0.0f;
    #pragma unroll 2
    for (int e = wg * 4 + rgrp; e < k32; e += 32) {
        float wv = kw[e];
        int row  = start + kidx[e];
        const float4 v = *(const float4*)(x + (size_t)row * 64 + fq * 4);
        a0 += v.x * wv; a1 += v.y * wv; a2 += v.z * wv; a3 += v.w * wv;
    }
    accs[wg][lane][0] = a0; accs[wg][lane][1] = a1;
    accs[wg][lane][2] = a2; accs[wg][lane][3] = a3;
    __syncthreads();
    if (tid < 64) {
        float sum = 0.0f;
        #pragma unroll
        for (int gg = 0; gg < 8; ++gg)
            #pragma unroll
            for (int rg = 0; rg < 4; ++rg)
                sum += accs[gg][rg * 16 + (tid >> 2)][tid & 3];
        out[(size_t)g * 64 + tid] = sum / fmaxf((float)k, 1.0f);
    }
}

extern "C" void kernel_launch(void* const* d_in, const int* in_sizes, int n_in,
                              void* d_out, int out_size, void* d_ws, size_t ws_size,
                              hipStream_t stream) {
    const float* x      = (const float*)d_in[0];
    const int*   ei     = (const int*)  d_in[1];
    const int*   batch  = (const int*)  d_in[2];
    const float* w_rel  = (const float*)d_in[3];
    const float* b_rel  = (const float*)d_in[4];
    const float* w_root = (const float*)d_in[5];
    float* out = (float*)d_out;

    int N = in_sizes[2];
    int E = in_sizes[1] / 2;
    int NBINS  = (N + BINR - 1) / BINR;
    int NBINSP = (NBINS + 15) & ~15;
    int chunkE = (((E + SBLK - 1) / SBLK) + 3) & ~3;
    int vecE   = ((E & 3) == 0);
    int dotblks = (N + 31) / 32;

    // ws layout (4B units): p[N], r[N], score[N], starts[256], ends[256],
    // (align16) Ct[NBINSP*SBLK], bucket u32[NBINSP*BINCAP]
    float* p      = (float*)d_ws;
    float* r      = p + (size_t)N;
    float* score  = r + (size_t)N;
    int*   starts = (int*)(score + (size_t)N);
    int*   ends   = starts + NGRAPHS;
    size_t coff = (size_t)3 * N + 2 * NGRAPHS;
    coff = (coff + 3) & ~(size_t)3;
    int* Ct = (int*)d_ws + coff;
    size_t boff = coff + (size_t)NBINSP * SBLK;
    unsigned* bucket = (unsigned*)d_ws + boff;
    size_t need = (boff + (size_t)NBINSP * BINCAP) * 4;

    // cell-overflow safety: mean edges per (block,bin) cell must be << CAPC
    double lam = (NBINS > 0) ? (double)chunkE / (double)NBINS : 0.0;
    bool binned = (need <= ws_size) && (NBINSP <= MAXB) && (E > 0)
                  && (N <= (1 << 17)) && (lam <= 8.0);

    if (binned) {
        kA_fused<<<SBLK + dotblks, 512, 0, stream>>>(
            x, batch, ei, w_rel, w_root, p, r, starts, ends, Ct, bucket,
            N, E, chunkE, NBINSP, vecE);
        kB_score<<<NBINS, 512, 0, stream>>>(bucket, Ct, p, r, b_rel, score, N);
    } else {
        float* aggdot = (float*)Ct;      // fallback-only alias
        kA_fused<<<SBLK + dotblks, 512, 0, stream>>>(
            x, batch, ei, w_rel, w_root, p, r, starts, ends, Ct, bucket,
            N, 0, 0, NBINSP, vecE);      // E=0: scatter blocks exit immediately
        kZ_zero<<<(N + 255) / 256, 256, 0, stream>>>(aggdot, N);
        k2_scatter<<<(E + 255) / 256, 256, 0, stream>>>(ei, p, aggdot, E);
        kS_score<<<(N + 255) / 256, 256, 0, stream>>>(aggdot, r, b_rel, score, N);
    }
    k4_pool<<<NGRAPHS, 512, 0, stream>>>(x, score, starts, ends, out);
}